// Round 1
// baseline (304.385 us; speedup 1.0000x reference)
//
#include <hip/hip_runtime.h>
#include <hip/hip_bf16.h>

// Problem constants (match reference)
#define B_   2
#define S_   2048
#define D_   512
#define H_   8
#define DK_  64
#define M_   (B_*S_)   // 4096 rows in the [B*S, D] view

typedef float  floatx4 __attribute__((ext_vector_type(4)));
typedef __bf16 bf16x8  __attribute__((ext_vector_type(8)));

#define MFMA16x16x32(a,b,c) __builtin_amdgcn_mfma_f32_16x16x32_bf16((a),(b),(c),0,0,0)

static __device__ inline bf16x8 load_f32_cvt8(const float* __restrict__ p) {
  float4 a = *(const float4*)p;
  float4 b = *(const float4*)(p + 4);
  bf16x8 r;
  r[0]=(__bf16)a.x; r[1]=(__bf16)a.y; r[2]=(__bf16)a.z; r[3]=(__bf16)a.w;
  r[4]=(__bf16)b.x; r[5]=(__bf16)b.y; r[6]=(__bf16)b.z; r[7]=(__bf16)b.w;
  return r;
}

// ---------------------------------------------------------------------------
// Kernel 1: convert the four 512x512 weight matrices fp32 -> bf16 (contiguous)
// out layout: [Wq | Wk | Wv | Wo], each 262144 elements.
// ---------------------------------------------------------------------------
__global__ __launch_bounds__(256) void cvt_weights(
    const float* __restrict__ w0, const float* __restrict__ w1,
    const float* __restrict__ w2, const float* __restrict__ w3,
    __bf16* __restrict__ out)
{
  int idx = (blockIdx.x * 256 + threadIdx.x) * 4;   // covers 4*262144 = 1048576
  int wsel = idx >> 18;            // 262144 = 2^18
  int off  = idx & 0x3FFFF;
  const float* src = (wsel == 0) ? w0 : (wsel == 1) ? w1 : (wsel == 2) ? w2 : w3;
  float4 v = *(const float4*)(src + off);
  __bf16* o = out + idx;
  o[0]=(__bf16)v.x; o[1]=(__bf16)v.y; o[2]=(__bf16)v.z; o[3]=(__bf16)v.w;
}

// ---------------------------------------------------------------------------
// Kernel 2: QKV projection.  C[m,n] = sum_k X[m,k]*W[n,k] + bias[n]
// grid = (M/64, D/64, 3); block = 256 (4 waves); wave computes 16(M) x 64(N).
// z=0 -> Q [B,H,S,DK] bf16 ; z=1 -> K [B,H,S,DK] bf16 ; z=2 -> Vt [B,H,DK,S] bf16
// ---------------------------------------------------------------------------
__global__ __launch_bounds__(256) void proj_qkv(
    const float* __restrict__ q_in, const float* __restrict__ k_in, const float* __restrict__ v_in,
    const __bf16* __restrict__ Wqb, const __bf16* __restrict__ Wkb, const __bf16* __restrict__ Wvb,
    const float* __restrict__ bq, const float* __restrict__ bk, const float* __restrict__ bv,
    __bf16* __restrict__ Qb, __bf16* __restrict__ Kb, __bf16* __restrict__ Vtb)
{
  const int z = blockIdx.z;
  const float*  X    = (z==0) ? q_in : (z==1) ? k_in : v_in;
  const __bf16* W    = (z==0) ? Wqb  : (z==1) ? Wkb  : Wvb;
  const float*  bias = (z==0) ? bq   : (z==1) ? bk   : bv;

  const int m0 = blockIdx.x * 64;
  const int n0 = blockIdx.y * 64;
  const int tid  = threadIdx.x;
  const int w    = tid >> 6;
  const int lane = tid & 63;
  const int lcol = lane & 15;        // A-row / B-row / C-col lane index
  const int quad = lane >> 4;        // k-slice selector

  const int mrow = m0 + w*16 + lcol;
  const float*  xp = X + (size_t)mrow * D_ + quad*8;
  const __bf16* wp = W + (size_t)(n0 + lcol) * D_ + quad*8;

  floatx4 zero = {0.f,0.f,0.f,0.f};
  floatx4 acc[4] = {zero, zero, zero, zero};

  for (int k = 0; k < D_; k += 32) {
    bf16x8 a = load_f32_cvt8(xp + k);
#pragma unroll
    for (int nt = 0; nt < 4; ++nt) {
      bf16x8 bfr = *(const bf16x8*)(wp + k + nt*16*D_);
      acc[nt] = MFMA16x16x32(a, bfr, acc[nt]);
    }
  }

  // epilogue: C/D layout col = lcol, row = quad*4 + r
#pragma unroll
  for (int nt = 0; nt < 4; ++nt) {
    const int n  = n0 + nt*16 + lcol;
    const float bv_ = bias[n];
    const int hh = n >> 6;       // head
    const int dk = n & 63;       // feature within head
#pragma unroll
    for (int r = 0; r < 4; ++r) {
      const int m  = m0 + w*16 + quad*4 + r;
      const int bb = m >> 11;            // batch (S=2048)
      const int ss = m & (S_ - 1);
      const float val = acc[nt][r] + bv_;
      if (z == 0) {
        Qb[((size_t)(bb*H_ + hh) * S_ + ss) * DK_ + dk] = (__bf16)val;
      } else if (z == 1) {
        Kb[((size_t)(bb*H_ + hh) * S_ + ss) * DK_ + dk] = (__bf16)val;
      } else {
        Vtb[((size_t)(bb*H_ + hh) * DK_ + dk) * S_ + ss] = (__bf16)val;
      }
    }
  }
}

// ---------------------------------------------------------------------------
// Kernel 3: causal flash attention.
// grid = (32, H, B); block = 256 (4 waves). Wave handles one 16-row Q tile.
// Heavy tiles mapped to low blockIdx.x so the scheduler backfills the tail.
// ---------------------------------------------------------------------------
__global__ __launch_bounds__(256) void attn_fwd(
    const __bf16* __restrict__ Qb, const __bf16* __restrict__ Kb,
    const __bf16* __restrict__ Vtb, __bf16* __restrict__ attnb)
{
  __shared__ __align__(16) __bf16 pbuf[4][16*32];   // per-wave P tile (16x32)

  const int tid  = threadIdx.x;
  const int w    = tid >> 6;
  const int lane = tid & 63;
  const int lcol = lane & 15;
  const int quad = lane >> 4;
  const int hh = blockIdx.y;
  const int bb = blockIdx.z;

  const int t  = 127 - (blockIdx.x * 4 + w);  // q-tile index, heavy first
  const int q0 = t * 16;

  const __bf16* Qp = Qb  + (size_t)(bb*H_ + hh) * S_ * DK_;
  const __bf16* Kp = Kb  + (size_t)(bb*H_ + hh) * S_ * DK_;
  const __bf16* Vp = Vtb + (size_t)(bb*H_ + hh) * DK_ * S_;

  // Q A-fragments: rows q0+lcol, k-slices [0,32) and [32,64)
  const bf16x8 aq0 = *(const bf16x8*)(Qp + (size_t)(q0 + lcol)*DK_ + quad*8);
  const bf16x8 aq1 = *(const bf16x8*)(Qp + (size_t)(q0 + lcol)*DK_ + 32 + quad*8);

  float mrow[4], lrow[4];
  floatx4 zero = {0.f,0.f,0.f,0.f};
  floatx4 acc[4] = {zero, zero, zero, zero};   // O tile: 4 N-tiles over DK=64
#pragma unroll
  for (int r = 0; r < 4; ++r) { mrow[r] = -1e30f; lrow[r] = 0.f; }

  const int kend = q0 + 16;                    // keys 0..q0+15 needed
  for (int k0 = 0; k0 < kend; k0 += 32) {
    // K B-fragments: rows (keys) k0+nt*16+lcol, same k-slices as Q
    bf16x8 kb00 = *(const bf16x8*)(Kp + (size_t)(k0      + lcol)*DK_      + quad*8);
    bf16x8 kb01 = *(const bf16x8*)(Kp + (size_t)(k0      + lcol)*DK_ + 32 + quad*8);
    bf16x8 kb10 = *(const bf16x8*)(Kp + (size_t)(k0 + 16 + lcol)*DK_      + quad*8);
    bf16x8 kb11 = *(const bf16x8*)(Kp + (size_t)(k0 + 16 + lcol)*DK_ + 32 + quad*8);

    floatx4 s0 = zero, s1 = zero;
    s0 = MFMA16x16x32(aq0, kb00, s0);
    s0 = MFMA16x16x32(aq1, kb01, s0);
    s1 = MFMA16x16x32(aq0, kb10, s1);
    s1 = MFMA16x16x32(aq1, kb11, s1);

    const bool edge = (k0 + 31 > q0);
    float p0[4], p1[4], alpha[4];
#pragma unroll
    for (int r = 0; r < 4; ++r) {
      float sv0 = s0[r] * 0.125f;
      float sv1 = s1[r] * 0.125f;
      if (edge) {
        const int qrow = q0 + quad*4 + r;
        if (k0      + lcol > qrow) sv0 = -1e30f;
        if (k0 + 16 + lcol > qrow) sv1 = -1e30f;
      }
      float cm = fmaxf(sv0, sv1);
      cm = fmaxf(cm, __shfl_xor(cm, 1, 16));
      cm = fmaxf(cm, __shfl_xor(cm, 2, 16));
      cm = fmaxf(cm, __shfl_xor(cm, 4, 16));
      cm = fmaxf(cm, __shfl_xor(cm, 8, 16));
      const float mnew = fmaxf(mrow[r], cm);
      const float a = __expf(mrow[r] - mnew);
      mrow[r] = mnew;
      p0[r] = __expf(sv0 - mnew);
      p1[r] = __expf(sv1 - mnew);
      float rs = p0[r] + p1[r];
      rs += __shfl_xor(rs, 1, 16);
      rs += __shfl_xor(rs, 2, 16);
      rs += __shfl_xor(rs, 4, 16);
      rs += __shfl_xor(rs, 8, 16);
      lrow[r] = lrow[r] * a + rs;
      alpha[r] = a;
    }
#pragma unroll
    for (int nt = 0; nt < 4; ++nt)
#pragma unroll
      for (int r = 0; r < 4; ++r) acc[nt][r] *= alpha[r];

    // P: C-layout -> LDS -> A-layout (m120-verified transform)
#pragma unroll
    for (int r = 0; r < 4; ++r) {
      const int row = quad*4 + r;
      pbuf[w][row*32 + lcol]      = (__bf16)p0[r];
      pbuf[w][row*32 + 16 + lcol] = (__bf16)p1[r];
    }
    asm volatile("s_waitcnt lgkmcnt(0)");
    const bf16x8 pa = *(const bf16x8*)(&pbuf[w][lcol*32 + quad*8]);

    // O += P @ V  with Vt[d][key]: B-frag rows are d = nt*16+lcol, k = keys
#pragma unroll
    for (int nt = 0; nt < 4; ++nt) {
      bf16x8 vb = *(const bf16x8*)(Vp + (size_t)(nt*16 + lcol)*S_ + k0 + quad*8);
      acc[nt] = MFMA16x16x32(pa, vb, acc[nt]);
    }
  }

  // normalize + store merged-head attention output [B,S,D] bf16
#pragma unroll
  for (int r = 0; r < 4; ++r) lrow[r] = 1.0f / lrow[r];
#pragma unroll
  for (int nt = 0; nt < 4; ++nt)
#pragma unroll
    for (int r = 0; r < 4; ++r) {
      const int q = q0 + quad*4 + r;
      attnb[((size_t)(bb*S_ + q)) * D_ + hh*DK_ + nt*16 + lcol] =
          (__bf16)(acc[nt][r] * lrow[r]);
    }
}

// ---------------------------------------------------------------------------
// Kernel 4: output projection. out[m,n] = sum_k attn[m,k]*Wo[n,k] + bo[n], fp32
// grid = (M/64, D/64); block = 256.
// ---------------------------------------------------------------------------
__global__ __launch_bounds__(256) void proj_out(
    const __bf16* __restrict__ attnb, const __bf16* __restrict__ Wob,
    const float* __restrict__ bo, float* __restrict__ out)
{
  const int m0 = blockIdx.x * 64;
  const int n0 = blockIdx.y * 64;
  const int tid  = threadIdx.x;
  const int w    = tid >> 6;
  const int lane = tid & 63;
  const int lcol = lane & 15;
  const int quad = lane >> 4;

  const int mrow = m0 + w*16 + lcol;
  const __bf16* ap = attnb + (size_t)mrow * D_ + quad*8;
  const __bf16* wp = Wob   + (size_t)(n0 + lcol) * D_ + quad*8;

  floatx4 zero = {0.f,0.f,0.f,0.f};
  floatx4 acc[4] = {zero, zero, zero, zero};

  for (int k = 0; k < D_; k += 32) {
    bf16x8 a = *(const bf16x8*)(ap + k);
#pragma unroll
    for (int nt = 0; nt < 4; ++nt) {
      bf16x8 bfr = *(const bf16x8*)(wp + k + nt*16*D_);
      acc[nt] = MFMA16x16x32(a, bfr, acc[nt]);
    }
  }

#pragma unroll
  for (int nt = 0; nt < 4; ++nt) {
    const int n = n0 + nt*16 + lcol;
    const float bv_ = bo[n];
#pragma unroll
    for (int r = 0; r < 4; ++r) {
      const int m = m0 + w*16 + quad*4 + r;
      out[(size_t)m * D_ + n] = acc[nt][r] + bv_;
    }
  }
}

// ---------------------------------------------------------------------------
extern "C" void kernel_launch(void* const* d_in, const int* in_sizes, int n_in,
                              void* d_out, int out_size, void* d_ws, size_t ws_size,
                              hipStream_t stream) {
  const float* q_in = (const float*)d_in[0];
  const float* k_in = (const float*)d_in[1];
  const float* v_in = (const float*)d_in[2];
  // d_in[3] = mask (causal tril) — implied by the kernel, unused
  const float* Wq = (const float*)d_in[4];
  const float* bq = (const float*)d_in[5];
  const float* Wk = (const float*)d_in[6];
  const float* bk = (const float*)d_in[7];
  const float* Wv = (const float*)d_in[8];
  const float* bv = (const float*)d_in[9];
  const float* Wo = (const float*)d_in[10];
  const float* bo = (const float*)d_in[11];
  float* out = (float*)d_out;

  __bf16* ws    = (__bf16*)d_ws;
  __bf16* Qb    = ws;                  // [B,H,S,DK]  2097152 el
  __bf16* Kb    = ws + 1*2097152;      // [B,H,S,DK]
  __bf16* Vtb   = ws + 2*2097152;      // [B,H,DK,S]
  __bf16* attnb = ws + 3*2097152;      // [B,S,D]
  __bf16* Wb    = ws + 4*2097152;      // Wq|Wk|Wv|Wo bf16, 262144 each

  cvt_weights<<<dim3(1024), dim3(256), 0, stream>>>(Wq, Wk, Wv, Wo, Wb);

  proj_qkv<<<dim3(M_/64, D_/64, 3), dim3(256), 0, stream>>>(
      q_in, k_in, v_in,
      Wb, Wb + 262144, Wb + 2*262144,
      bq, bk, bv,
      Qb, Kb, Vtb);

  attn_fwd<<<dim3(32, H_, B_), dim3(256), 0, stream>>>(Qb, Kb, Vtb, attnb);

  proj_out<<<dim3(M_/64, D_/64), dim3(256), 0, stream>>>(
      attnb, Wb + 3*262144, bo, out);
}